// Round 1
// baseline (3276.137 us; speedup 1.0000x reference)
//
#include <hip/hip_runtime.h>
#include <stdint.h>
#include <stddef.h>

// ---------------------------------------------------------------------------
// BoundingBox loss processor:
//   filter (maxconf > 0.6) -> sort by class-0 score desc (stable, idx asc)
//   -> greedy NMS (IoU > 0.5 suppress) -> per-class top-20 over kept
//   -> smooth-L1 vs targets + focal CE on (class0 top-20 > 0.5) -> /M
// ---------------------------------------------------------------------------

#define NCAP 8192
#define WROW (NCAP / 64)   // 128 u64 words per mask row

// ---------------- workspace layout (all offsets 8-byte aligned) ------------
constexpr size_t OFF_CNT   = 0;                               // 2 x u32 counters: [0]=F, [1]=M
constexpr size_t OFF_KEYS  = 256;                             // u64[NCAP]
constexpr size_t OFF_SX1   = OFF_KEYS + 8ull * NCAP;          // f32[NCAP]
constexpr size_t OFF_SY1   = OFF_SX1 + 4ull * NCAP;
constexpr size_t OFF_SX2   = OFF_SY1 + 4ull * NCAP;
constexpr size_t OFF_SY2   = OFF_SX2 + 4ull * NCAP;
constexpr size_t OFF_AREA  = OFF_SY2 + 4ull * NCAP;
constexpr size_t OFF_SORIG = OFF_AREA + 4ull * NCAP;          // u32[NCAP] sorted->orig row
constexpr size_t OFF_KEEPS = OFF_SORIG + 4ull * NCAP;         // u32[NCAP] kept (sorted-space)
constexpr size_t OFF_KORIG = OFF_KEEPS + 4ull * NCAP;         // u32[NCAP] kept -> orig row
constexpr size_t OFF_TOPV  = OFF_KORIG + 4ull * NCAP;         // f32[1024] topv[c*KT+t]
constexpr size_t OFF_TOPI  = OFF_TOPV + 4096;                 // i32[1024]
constexpr size_t OFF_MASK  = OFF_TOPI + 4096;                 // u64[NCAP*WROW] = 8 MB
constexpr size_t WS_NEED_MASK = OFF_MASK + 8ull * NCAP * WROW;

// ---------------- kernels ---------------------------------------------------

__global__ void k_init(unsigned int* cnt) {
  if (threadIdx.x < 2) cnt[threadIdx.x] = 0u;
}

// Per row: valid = max over C confs > 0.6; sort key = desc(class0 score) | row.
__global__ void k_filter(const float* __restrict__ conf, int N, int C,
                         unsigned long long* __restrict__ keys,
                         unsigned int* __restrict__ cnt) {
  int row = blockIdx.x * blockDim.x + threadIdx.x;
  if (row >= NCAP) return;
  unsigned long long key;
  if (row < N) {
    const float* cr = conf + (size_t)row * C;
    float mx = cr[0];
    for (int c = 1; c < C; ++c) mx = fmaxf(mx, cr[c]);
    unsigned int k32;
    if (mx > 0.6f) {
      union { float f; unsigned int u; } s; s.f = cr[0];
      unsigned int u = s.u;
      // monotone float->uint (ascending), then invert for descending sort
      u = (u & 0x80000000u) ? ~u : (u | 0x80000000u);
      k32 = ~u;
      if (k32 == 0xFFFFFFFFu) k32 = 0xFFFFFFFEu;  // keep 0xFFFFFFFF = invalid
      atomicAdd(&cnt[0], 1u);
    } else {
      k32 = 0xFFFFFFFFu;  // invalid rows sort last
    }
    key = ((unsigned long long)k32 << 32) | (unsigned int)row;
  } else {
    key = ((unsigned long long)0xFFFFFFFFu << 32);  // pad, row 0 (never used < F)
  }
  keys[row] = key;
}

// One-block LDS bitonic sort, ascending u64 (desc score, asc row on ties).
__global__ __launch_bounds__(1024) void k_sort(unsigned long long* __restrict__ keys) {
  __shared__ unsigned long long sk[NCAP];  // 64 KiB
  int tid = threadIdx.x;
  for (int t = tid; t < NCAP; t += 1024) sk[t] = keys[t];
  __syncthreads();
  for (unsigned int k = 2; k <= NCAP; k <<= 1) {
    for (unsigned int j = k >> 1; j > 0; j >>= 1) {
      for (int t = tid; t < NCAP; t += 1024) {
        unsigned int p = (unsigned int)t ^ j;
        if (p > (unsigned int)t) {
          bool up = ((t & k) == 0);
          unsigned long long x = sk[t], y = sk[p];
          bool sw = up ? (x > y) : (x < y);
          if (sw) { sk[t] = y; sk[p] = x; }
        }
      }
      __syncthreads();
    }
  }
  for (int t = tid; t < NCAP; t += 1024) keys[t] = sk[t];
}

// Gather boxes into sorted order, precompute areas.
__global__ void k_gather(const float* __restrict__ loc,
                         const unsigned long long* __restrict__ keys,
                         float* __restrict__ sx1, float* __restrict__ sy1,
                         float* __restrict__ sx2, float* __restrict__ sy2,
                         float* __restrict__ sarea, unsigned int* __restrict__ sorig) {
  int p = blockIdx.x * blockDim.x + threadIdx.x;
  if (p >= NCAP) return;
  unsigned int row = (unsigned int)(keys[p] & 0xFFFFFFFFull);
  const float* b = loc + (size_t)row * 4;
  float x1 = b[0], y1 = b[1], x2 = b[2], y2 = b[3];
  sx1[p] = x1; sy1[p] = y1; sx2[p] = x2; sy2[p] = y2;
  sarea[p] = (x2 - x1) * (y2 - y1);   // numpy op order, no FMA hazard
  sorig[p] = row;
}

// Pairwise IoU>0.5 bitmask, torchvision style: 64x64 tiles, 1 wave per block.
__global__ __launch_bounds__(64) void k_mask(
    const float* __restrict__ sx1, const float* __restrict__ sy1,
    const float* __restrict__ sx2, const float* __restrict__ sy2,
    const float* __restrict__ sarea,
    unsigned long long* __restrict__ mask) {
  __shared__ float jx1[64], jy1[64], jx2[64], jy2[64], ja[64];
  int t = threadIdx.x;
  int jbase = blockIdx.y * 64;
  jx1[t] = sx1[jbase + t]; jy1[t] = sy1[jbase + t];
  jx2[t] = sx2[jbase + t]; jy2[t] = sy2[jbase + t];
  ja[t]  = sarea[jbase + t];
  __syncthreads();
  int i = blockIdx.x * 64 + t;
  float xi1 = sx1[i], yi1 = sy1[i], xi2 = sx2[i], yi2 = sy2[i], ai = sarea[i];
  unsigned long long bits = 0ULL;
#pragma unroll 8
  for (int jj = 0; jj < 64; ++jj) {
    float xx1 = fmaxf(xi1, jx1[jj]);
    float yy1 = fmaxf(yi1, jy1[jj]);
    float xx2 = fminf(xi2, jx2[jj]);
    float yy2 = fminf(yi2, jy2[jj]);
    float w = fmaxf(xx2 - xx1, 0.0f);
    float h = fmaxf(yy2 - yy1, 0.0f);
    float inter = w * h;
    float den = ai + ja[jj] - inter;   // (ai + aj) - inter, numpy order
    float iou = inter / den;           // IEEE div; 0/0 -> NaN -> compare false
    if (iou > 0.5f) bits |= (1ULL << jj);
  }
  mask[(size_t)i * WROW + blockIdx.y] = bits;
}

// Sequential greedy scan: one wave, removed-bitset in registers (2 u64/lane),
// ping-pong prefetch of 8-row chunks to hide L2 latency.
__global__ __launch_bounds__(64) void k_scan(
    const unsigned long long* __restrict__ mask,
    unsigned int* __restrict__ cnt,
    unsigned int* __restrict__ keeps) {
  const int lane = threadIdx.x;   // 0..63
  const int F = (int)cnt[0];
  unsigned long long rem0 = 0ULL, rem1 = 0ULL;
  int K = 0;
  unsigned long long a0[8], a1[8], b0[8], b1[8];

  auto load = [&](int base, unsigned long long* c0, unsigned long long* c1) {
#pragma unroll
    for (int r = 0; r < 8; ++r) {
      int i = base + r;
      if (i < F) {
        const unsigned long long* row = mask + (size_t)i * WROW;
        c0[r] = row[2 * lane];
        c1[r] = row[2 * lane + 1];
      }
    }
  };
  auto process = [&](int base, const unsigned long long* c0, const unsigned long long* c1) {
#pragma unroll
    for (int r = 0; r < 8; ++r) {
      int i = base + r;
      if (i >= F) break;
      int w = i >> 6;                       // which u64 word holds bit i
      unsigned long long word = (w & 1) ? rem1 : rem0;
      bool sup = (lane == (w >> 1)) && ((word >> (i & 63)) & 1ULL);
      if (__ballot(sup) == 0ULL) {          // not suppressed -> keep
        if (lane == 0) keeps[K] = (unsigned int)i;
        ++K;
        rem0 |= c0[r];
        rem1 |= c1[r];
      }
    }
  };

  if (F > 0) {
    load(0, a0, a1);
    int base = 0;
    while (true) {
      load(base + 8, b0, b1);
      process(base, a0, a1);
      base += 8;
      if (base >= F) break;
      load(base + 8, a0, a1);
      process(base, b0, b1);
      base += 8;
      if (base >= F) break;
    }
  }
  if (lane == 0) cnt[1] = (unsigned int)K;
}

// Fallback (small workspace): on-the-fly IoU greedy scan in one block.
__global__ __launch_bounds__(256) void k_scan_nomask(
    const float* __restrict__ sx1, const float* __restrict__ sy1,
    const float* __restrict__ sx2, const float* __restrict__ sy2,
    const float* __restrict__ sarea,
    unsigned int* __restrict__ cnt,
    unsigned int* __restrict__ keeps) {
  __shared__ unsigned char sup[NCAP];
  __shared__ int sK;
  int tid = threadIdx.x;
  int F = (int)cnt[0];
  for (int j = tid; j < NCAP; j += 256) sup[j] = 0;
  if (tid == 0) sK = 0;
  __syncthreads();
  for (int i = 0; i < F; ++i) {
    if (!sup[i]) {                      // uniform branch
      if (tid == 0) keeps[sK++] = (unsigned int)i;
      float xi1 = sx1[i], yi1 = sy1[i], xi2 = sx2[i], yi2 = sy2[i], ai = sarea[i];
      for (int j = i + 1 + tid; j < F; j += 256) {
        if (sup[j]) continue;
        float xx1 = fmaxf(xi1, sx1[j]);
        float yy1 = fmaxf(yi1, sy1[j]);
        float xx2 = fminf(xi2, sx2[j]);
        float yy2 = fminf(yi2, sy2[j]);
        float w = fmaxf(xx2 - xx1, 0.0f);
        float h = fmaxf(yy2 - yy1, 0.0f);
        float inter = w * h;
        float iou = inter / (ai + sarea[j] - inter);
        if (iou > 0.5f) sup[j] = 1;
      }
    }
    __syncthreads();
  }
  if (tid == 0) cnt[1] = (unsigned int)sK;
}

// kept (sorted-space) -> original row indices
__global__ void k_keptorig(const unsigned int* __restrict__ sorig,
                           const unsigned int* __restrict__ keeps,
                           unsigned int* __restrict__ korig,
                           const unsigned int* __restrict__ cnt) {
  int j = blockIdx.x * blockDim.x + threadIdx.x;
  if (j < (int)cnt[1]) korig[j] = sorig[keeps[j]];
}

// Per class (block), top-KT over the M kept boxes; lax.top_k tie semantics
// (descending value, lower index wins ties).
__global__ __launch_bounds__(256) void k_topk(
    const float* __restrict__ conf,
    const unsigned int* __restrict__ korig,
    const unsigned int* __restrict__ cnt,
    int C, int KT,
    float* __restrict__ topv, int* __restrict__ topi) {
  __shared__ float col[NCAP];
  __shared__ unsigned char flags[NCAP];
  __shared__ float rv[256];
  __shared__ int ri[256];
  int tid = threadIdx.x;
  int c = blockIdx.x;
  int M = (int)cnt[1];
  for (int j = tid; j < M; j += 256) {
    col[j] = conf[(size_t)korig[j] * C + c];
    flags[j] = 0;
  }
  __syncthreads();
  for (int t = 0; t < KT; ++t) {
    float bv = -3.402823466e+38f;
    int bj = 0x7FFFFFFF;
    for (int j = tid; j < M; j += 256) {
      if (flags[j]) continue;
      float v = col[j];
      if (v > bv || (v == bv && j < bj)) { bv = v; bj = j; }
    }
    rv[tid] = bv; ri[tid] = bj;
    __syncthreads();
    for (int s = 128; s > 0; s >>= 1) {
      if (tid < s) {
        float v2 = rv[tid + s]; int j2 = ri[tid + s];
        if (v2 > rv[tid] || (v2 == rv[tid] && j2 < ri[tid])) { rv[tid] = v2; ri[tid] = j2; }
      }
      __syncthreads();
    }
    if (tid == 0) {
      int w = ri[0];
      if (w == 0x7FFFFFFF) w = 0;    // M < KT safety; reference would crash here
      else flags[w] = 1;
      topv[c * KT + t] = rv[0];
      topi[c * KT + t] = w;
    }
    __syncthreads();
  }
}

// Final scalar: smooth-L1 over (KT, C, 4) gathered boxes + focal CE on
// (class0 top-KT > 0.5), divided by M.
__global__ __launch_bounds__(256) void k_loss(
    const float* __restrict__ loc, const float* __restrict__ tb,
    const int* __restrict__ labels,
    const unsigned int* __restrict__ korig,
    const float* __restrict__ topv, const int* __restrict__ topi,
    const unsigned int* __restrict__ cnt, int C, int KT,
    float* __restrict__ out) {
  __shared__ float red[256];
  int tid = threadIdx.x;
  int F = (int)cnt[0];
  int M = (int)cnt[1];
  if (F == 0 || M == 0) {
    if (tid == 0) out[0] = 0.001f;
    return;
  }
  int total = KT * C * 4;
  float part = 0.0f;
  for (int e = tid; e < total; e += 256) {
    int d = e & 3;
    int q = e >> 2;
    int c = q % C;
    int i = q / C;
    int j = topi[c * KT + i];
    unsigned int orow = korig[j];
    float pred = loc[(size_t)orow * 4 + d];
    float tg = tb[c * 4 + d];
    float dd = fabsf(pred - tg);
    part += (dd < 1.0f) ? (0.5f * dd * dd) : (dd - 0.5f);
  }
  red[tid] = part;
  __syncthreads();
  for (int s = 128; s > 0; s >>= 1) {
    if (tid < s) red[tid] += red[tid + s];
    __syncthreads();
  }
  if (tid == 0) {
    float loc_loss = red[0];
    float mx = -3.402823466e+38f;
    for (int i = 0; i < KT; ++i) {
      float x = (topv[i] > 0.5f) ? 1.0f : 0.0f;   // class 0 column
      mx = fmaxf(mx, x);
    }
    float ssum = 0.0f;
    for (int i = 0; i < KT; ++i) {
      float x = (topv[i] > 0.5f) ? 1.0f : 0.0f;
      ssum += expf(x - mx);
    }
    float lse = mx + logf(ssum);
    float ce = 0.0f;
    for (int i = 0; i < KT; ++i) {
      float x = (topv[i] > 0.5f) ? 1.0f : 0.0f;
      ce += (float)labels[i] * (x - lse);
    }
    ce = -ce;
    float pt = expf(-ce);
    float om = 1.0f - pt;
    float conf_loss = 0.25f * om * om * ce;   // ALPHA=0.25, GAMMA=2
    out[0] = (loc_loss + conf_loss) / (float)M;
  }
}

// ---------------- host ------------------------------------------------------

extern "C" void kernel_launch(void* const* d_in, const int* in_sizes, int n_in,
                              void* d_out, int out_size, void* d_ws, size_t ws_size,
                              hipStream_t stream) {
  (void)n_in; (void)out_size;
  const float* loc    = (const float*)d_in[0];
  const float* conf   = (const float*)d_in[1];
  const float* tb     = (const float*)d_in[2];
  const int*   labels = (const int*)d_in[3];
  float* out = (float*)d_out;

  int N = in_sizes[0] / 4;
  if (N > NCAP) N = NCAP;
  int C  = (N > 0) ? (in_sizes[1] / N) : 20;
  int KT = in_sizes[3];

  char* ws = (char*)d_ws;
  unsigned int*       cnt   = (unsigned int*)(ws + OFF_CNT);
  unsigned long long* keys  = (unsigned long long*)(ws + OFF_KEYS);
  float*              sx1   = (float*)(ws + OFF_SX1);
  float*              sy1   = (float*)(ws + OFF_SY1);
  float*              sx2   = (float*)(ws + OFF_SX2);
  float*              sy2   = (float*)(ws + OFF_SY2);
  float*              sarea = (float*)(ws + OFF_AREA);
  unsigned int*       sorig = (unsigned int*)(ws + OFF_SORIG);
  unsigned int*       keeps = (unsigned int*)(ws + OFF_KEEPS);
  unsigned int*       korig = (unsigned int*)(ws + OFF_KORIG);
  float*              topv  = (float*)(ws + OFF_TOPV);
  int*                topi  = (int*)(ws + OFF_TOPI);
  unsigned long long* mask  = (unsigned long long*)(ws + OFF_MASK);

  bool use_mask = (ws_size >= WS_NEED_MASK);

  k_init<<<1, 64, 0, stream>>>(cnt);
  k_filter<<<NCAP / 256, 256, 0, stream>>>(conf, N, C, keys, cnt);
  k_sort<<<1, 1024, 0, stream>>>(keys);
  k_gather<<<NCAP / 256, 256, 0, stream>>>(loc, keys, sx1, sy1, sx2, sy2, sarea, sorig);
  if (use_mask) {
    k_mask<<<dim3(WROW, WROW), 64, 0, stream>>>(sx1, sy1, sx2, sy2, sarea, mask);
    k_scan<<<1, 64, 0, stream>>>(mask, cnt, keeps);
  } else {
    k_scan_nomask<<<1, 256, 0, stream>>>(sx1, sy1, sx2, sy2, sarea, cnt, keeps);
  }
  k_keptorig<<<NCAP / 256, 256, 0, stream>>>(sorig, keeps, korig, cnt);
  k_topk<<<C, 256, 0, stream>>>(conf, korig, cnt, C, KT, topv, topi);
  k_loss<<<1, 256, 0, stream>>>(loc, tb, labels, korig, topv, topi, cnt, C, KT, out);
}

// Round 2
// 1118.001 us; speedup vs baseline: 2.9304x; 2.9304x over previous
//
#include <hip/hip_runtime.h>
#include <stdint.h>
#include <stddef.h>

// ---------------------------------------------------------------------------
// BoundingBox loss processor:
//   filter (maxconf > 0.6) -> sort by class-0 score desc (stable, idx asc)
//   -> greedy NMS (IoU > 0.5 suppress) -> per-class top-20 over kept
//   -> smooth-L1 vs targets + focal CE on (class0 top-20 > 0.5) -> /M
// ---------------------------------------------------------------------------

#define NCAP 8192
#define WROW (NCAP / 64)   // 128 u64 words per mask row

// ---------------- workspace layout (all offsets 16-byte aligned) -----------
constexpr size_t OFF_CNT   = 0;                               // 2 x u32 counters: [0]=F, [1]=M
constexpr size_t OFF_KEYS  = 256;                             // u64[NCAP]
constexpr size_t OFF_SX1   = OFF_KEYS + 8ull * NCAP;          // f32[NCAP]
constexpr size_t OFF_SY1   = OFF_SX1 + 4ull * NCAP;
constexpr size_t OFF_SX2   = OFF_SY1 + 4ull * NCAP;
constexpr size_t OFF_SY2   = OFF_SX2 + 4ull * NCAP;
constexpr size_t OFF_AREA  = OFF_SY2 + 4ull * NCAP;
constexpr size_t OFF_SORIG = OFF_AREA + 4ull * NCAP;          // u32[NCAP] sorted->orig row
constexpr size_t OFF_KEEPS = OFF_SORIG + 4ull * NCAP;         // u32[NCAP] kept (sorted-space)
constexpr size_t OFF_KORIG = OFF_KEEPS + 4ull * NCAP;         // u32[NCAP] kept -> orig row
constexpr size_t OFF_TOPV  = OFF_KORIG + 4ull * NCAP;         // f32[1024] topv[c*KT+t]
constexpr size_t OFF_TOPI  = OFF_TOPV + 4096;                 // i32[1024]
constexpr size_t OFF_MASK  = OFF_TOPI + 4096;                 // u64[NCAP*WROW] = 8 MB
constexpr size_t WS_NEED_MASK = OFF_MASK + 8ull * NCAP * WROW;

// ---------------- kernels ---------------------------------------------------

__global__ void k_init(unsigned int* cnt) {
  if (threadIdx.x < 2) cnt[threadIdx.x] = 0u;
}

// Per row: valid = max over C confs > 0.6; sort key = desc(class0 score) | row.
__global__ void k_filter(const float* __restrict__ conf, int N, int C,
                         unsigned long long* __restrict__ keys,
                         unsigned int* __restrict__ cnt) {
  int row = blockIdx.x * blockDim.x + threadIdx.x;
  if (row >= NCAP) return;
  unsigned long long key;
  if (row < N) {
    const float* cr = conf + (size_t)row * C;
    float mx = cr[0];
    for (int c = 1; c < C; ++c) mx = fmaxf(mx, cr[c]);
    unsigned int k32;
    if (mx > 0.6f) {
      union { float f; unsigned int u; } s; s.f = cr[0];
      unsigned int u = s.u;
      // monotone float->uint (ascending), then invert for descending sort
      u = (u & 0x80000000u) ? ~u : (u | 0x80000000u);
      k32 = ~u;
      if (k32 == 0xFFFFFFFFu) k32 = 0xFFFFFFFEu;  // keep 0xFFFFFFFF = invalid
      atomicAdd(&cnt[0], 1u);
    } else {
      k32 = 0xFFFFFFFFu;  // invalid rows sort last
    }
    key = ((unsigned long long)k32 << 32) | (unsigned int)row;
  } else {
    key = ((unsigned long long)0xFFFFFFFFu << 32);  // pad, row 0 (never used < F)
  }
  keys[row] = key;
}

// One-block LDS bitonic sort, ascending u64 (desc score, asc row on ties).
__global__ __launch_bounds__(1024) void k_sort(unsigned long long* __restrict__ keys) {
  __shared__ unsigned long long sk[NCAP];  // 64 KiB
  int tid = threadIdx.x;
  for (int t = tid; t < NCAP; t += 1024) sk[t] = keys[t];
  __syncthreads();
  for (unsigned int k = 2; k <= NCAP; k <<= 1) {
    for (unsigned int j = k >> 1; j > 0; j >>= 1) {
      for (int t = tid; t < NCAP; t += 1024) {
        unsigned int p = (unsigned int)t ^ j;
        if (p > (unsigned int)t) {
          bool up = ((t & k) == 0);
          unsigned long long x = sk[t], y = sk[p];
          bool sw = up ? (x > y) : (x < y);
          if (sw) { sk[t] = y; sk[p] = x; }
        }
      }
      __syncthreads();
    }
  }
  for (int t = tid; t < NCAP; t += 1024) keys[t] = sk[t];
}

// Gather boxes into sorted order, precompute areas.
__global__ void k_gather(const float* __restrict__ loc,
                         const unsigned long long* __restrict__ keys,
                         float* __restrict__ sx1, float* __restrict__ sy1,
                         float* __restrict__ sx2, float* __restrict__ sy2,
                         float* __restrict__ sarea, unsigned int* __restrict__ sorig) {
  int p = blockIdx.x * blockDim.x + threadIdx.x;
  if (p >= NCAP) return;
  unsigned int row = (unsigned int)(keys[p] & 0xFFFFFFFFull);
  const float* b = loc + (size_t)row * 4;
  float x1 = b[0], y1 = b[1], x2 = b[2], y2 = b[3];
  sx1[p] = x1; sy1[p] = y1; sx2[p] = x2; sy2[p] = y2;
  sarea[p] = (x2 - x1) * (y2 - y1);   // numpy op order, no FMA hazard
  sorig[p] = row;
}

// Pairwise IoU>0.5 bitmask, torchvision style: 64x64 tiles, 1 wave per block.
__global__ __launch_bounds__(64) void k_mask(
    const float* __restrict__ sx1, const float* __restrict__ sy1,
    const float* __restrict__ sx2, const float* __restrict__ sy2,
    const float* __restrict__ sarea,
    unsigned long long* __restrict__ mask) {
  __shared__ float jx1[64], jy1[64], jx2[64], jy2[64], ja[64];
  int t = threadIdx.x;
  int jbase = blockIdx.y * 64;
  jx1[t] = sx1[jbase + t]; jy1[t] = sy1[jbase + t];
  jx2[t] = sx2[jbase + t]; jy2[t] = sy2[jbase + t];
  ja[t]  = sarea[jbase + t];
  __syncthreads();
  int i = blockIdx.x * 64 + t;
  float xi1 = sx1[i], yi1 = sy1[i], xi2 = sx2[i], yi2 = sy2[i], ai = sarea[i];
  unsigned long long bits = 0ULL;
#pragma unroll 8
  for (int jj = 0; jj < 64; ++jj) {
    float xx1 = fmaxf(xi1, jx1[jj]);
    float yy1 = fmaxf(yi1, jy1[jj]);
    float xx2 = fminf(xi2, jx2[jj]);
    float yy2 = fminf(yi2, jy2[jj]);
    float w = fmaxf(xx2 - xx1, 0.0f);
    float h = fmaxf(yy2 - yy1, 0.0f);
    float inter = w * h;
    float den = ai + ja[jj] - inter;   // (ai + aj) - inter, numpy order
    float iou = inter / den;           // IEEE div; 0/0 -> NaN -> compare false
    if (iou > 0.5f) bits |= (1ULL << jj);
  }
  mask[(size_t)i * WROW + blockIdx.y] = bits;
}

// ---------------------------------------------------------------------------
// Sequential greedy scan: one wave, removed-bitset in registers (2 u64/lane).
// Software pipeline: 4 chunks x 8 rows = 32 rows (= 32 x 16B loads/lane) in
// flight. Buffers are named locals touched only with compile-time indices in
// macro-expanded unrolled loops -> SROA keeps them in VGPRs (round-1 version
// passed them as pointers into lambdas -> scratch spill -> 870 cyc/row).
// ---------------------------------------------------------------------------
#define SCAN_CH 8

#define LOADC(B, base_) do {                                                  \
    const int _b = (base_);                                                   \
    _Pragma("unroll")                                                         \
    for (int _r = 0; _r < SCAN_CH; ++_r) {                                    \
      int _i = _b + _r;                                                       \
      int _ic = (_i < NCAP) ? _i : (NCAP - 1);  /* clamp: value unused */     \
      B##_##_r? 0 : 0;                                                        \
    }                                                                         \
  } while (0)

// (macro above replaced by explicit functions below — see LOAD8/PROC8)

__device__ __forceinline__ void load8(const ulonglong2* __restrict__ mrow,
                                      int lane, int base,
                                      ulonglong2 (&B)[SCAN_CH]) {
#pragma unroll
  for (int r = 0; r < SCAN_CH; ++r) {
    int i = base + r;
    int ic = (i < NCAP) ? i : (NCAP - 1);   // clamp: value unused when i >= F
    B[r] = mrow[(size_t)ic * 64 + lane];
  }
}

__device__ __forceinline__ void proc8(int lane, int base, int F,
                                      ulonglong2 (&B)[SCAN_CH],
                                      unsigned long long& rem0,
                                      unsigned long long& rem1,
                                      int& K, unsigned int* __restrict__ keeps) {
#pragma unroll
  for (int r = 0; r < SCAN_CH; ++r) {
    int i = base + r;
    if (i >= F) break;
    int w = i >> 6;                           // u64 word holding bit i
    unsigned long long word = (w & 1) ? rem1 : rem0;
    bool sup = (lane == (w >> 1)) && ((word >> (i & 63)) & 1ULL);
    if (__ballot(sup) == 0ULL) {              // not suppressed -> keep
      if (lane == 0) keeps[K] = (unsigned int)i;
      ++K;
      rem0 |= B[r].x;
      rem1 |= B[r].y;
    }
  }
}

__global__ __launch_bounds__(64) void k_scan(
    const unsigned long long* __restrict__ mask,
    unsigned int* __restrict__ cnt,
    unsigned int* __restrict__ keeps) {
  const int lane = threadIdx.x;   // 0..63; lane owns words 2*lane, 2*lane+1
  const int F = (int)cnt[0];
  const ulonglong2* mrow = (const ulonglong2*)mask;  // 64 ulonglong2 per row
  unsigned long long rem0 = 0ULL, rem1 = 0ULL;
  int K = 0;

  ulonglong2 p0[SCAN_CH], p1[SCAN_CH], p2[SCAN_CH], p3[SCAN_CH];

  if (F > 0) {
    load8(mrow, lane, 0 * SCAN_CH, p0);
    load8(mrow, lane, 1 * SCAN_CH, p1);
    load8(mrow, lane, 2 * SCAN_CH, p2);
    load8(mrow, lane, 3 * SCAN_CH, p3);
    int base = 0;
    while (true) {
      proc8(lane, base, F, p0, rem0, rem1, K, keeps);
      load8(mrow, lane, base + 4 * SCAN_CH, p0);
      base += SCAN_CH; if (base >= F) break;
      proc8(lane, base, F, p1, rem0, rem1, K, keeps);
      load8(mrow, lane, base + 4 * SCAN_CH, p1);
      base += SCAN_CH; if (base >= F) break;
      proc8(lane, base, F, p2, rem0, rem1, K, keeps);
      load8(mrow, lane, base + 4 * SCAN_CH, p2);
      base += SCAN_CH; if (base >= F) break;
      proc8(lane, base, F, p3, rem0, rem1, K, keeps);
      load8(mrow, lane, base + 4 * SCAN_CH, p3);
      base += SCAN_CH; if (base >= F) break;
    }
  }
  if (lane == 0) cnt[1] = (unsigned int)K;
}

// Fallback (small workspace): on-the-fly IoU greedy scan in one block.
__global__ __launch_bounds__(256) void k_scan_nomask(
    const float* __restrict__ sx1, const float* __restrict__ sy1,
    const float* __restrict__ sx2, const float* __restrict__ sy2,
    const float* __restrict__ sarea,
    unsigned int* __restrict__ cnt,
    unsigned int* __restrict__ keeps) {
  __shared__ unsigned char sup[NCAP];
  __shared__ int sK;
  int tid = threadIdx.x;
  int F = (int)cnt[0];
  for (int j = tid; j < NCAP; j += 256) sup[j] = 0;
  if (tid == 0) sK = 0;
  __syncthreads();
  for (int i = 0; i < F; ++i) {
    if (!sup[i]) {                      // uniform branch
      if (tid == 0) keeps[sK++] = (unsigned int)i;
      float xi1 = sx1[i], yi1 = sy1[i], xi2 = sx2[i], yi2 = sy2[i], ai = sarea[i];
      for (int j = i + 1 + tid; j < F; j += 256) {
        if (sup[j]) continue;
        float xx1 = fmaxf(xi1, sx1[j]);
        float yy1 = fmaxf(yi1, sy1[j]);
        float xx2 = fminf(xi2, sx2[j]);
        float yy2 = fminf(yi2, sy2[j]);
        float w = fmaxf(xx2 - xx1, 0.0f);
        float h = fmaxf(yy2 - yy1, 0.0f);
        float inter = w * h;
        float iou = inter / (ai + sarea[j] - inter);
        if (iou > 0.5f) sup[j] = 1;
      }
    }
    __syncthreads();
  }
  if (tid == 0) cnt[1] = (unsigned int)sK;
}

// kept (sorted-space) -> original row indices
__global__ void k_keptorig(const unsigned int* __restrict__ sorig,
                           const unsigned int* __restrict__ keeps,
                           unsigned int* __restrict__ korig,
                           const unsigned int* __restrict__ cnt) {
  int j = blockIdx.x * blockDim.x + threadIdx.x;
  if (j < (int)cnt[1]) korig[j] = sorig[keeps[j]];
}

// Per class (block), top-KT over the M kept boxes; lax.top_k tie semantics
// (descending value, lower index wins ties).
__global__ __launch_bounds__(256) void k_topk(
    const float* __restrict__ conf,
    const unsigned int* __restrict__ korig,
    const unsigned int* __restrict__ cnt,
    int C, int KT,
    float* __restrict__ topv, int* __restrict__ topi) {
  __shared__ float col[NCAP];
  __shared__ unsigned char flags[NCAP];
  __shared__ float rv[256];
  __shared__ int ri[256];
  int tid = threadIdx.x;
  int c = blockIdx.x;
  int M = (int)cnt[1];
  for (int j = tid; j < M; j += 256) {
    col[j] = conf[(size_t)korig[j] * C + c];
    flags[j] = 0;
  }
  __syncthreads();
  for (int t = 0; t < KT; ++t) {
    float bv = -3.402823466e+38f;
    int bj = 0x7FFFFFFF;
    for (int j = tid; j < M; j += 256) {
      if (flags[j]) continue;
      float v = col[j];
      if (v > bv || (v == bv && j < bj)) { bv = v; bj = j; }
    }
    rv[tid] = bv; ri[tid] = bj;
    __syncthreads();
    for (int s = 128; s > 0; s >>= 1) {
      if (tid < s) {
        float v2 = rv[tid + s]; int j2 = ri[tid + s];
        if (v2 > rv[tid] || (v2 == rv[tid] && j2 < ri[tid])) { rv[tid] = v2; ri[tid] = j2; }
      }
      __syncthreads();
    }
    if (tid == 0) {
      int w = ri[0];
      if (w == 0x7FFFFFFF) w = 0;    // M < KT safety; reference would crash here
      else flags[w] = 1;
      topv[c * KT + t] = rv[0];
      topi[c * KT + t] = w;
    }
    __syncthreads();
  }
}

// Final scalar: smooth-L1 over (KT, C, 4) gathered boxes + focal CE on
// (class0 top-KT > 0.5), divided by M.
__global__ __launch_bounds__(256) void k_loss(
    const float* __restrict__ loc, const float* __restrict__ tb,
    const int* __restrict__ labels,
    const unsigned int* __restrict__ korig,
    const float* __restrict__ topv, const int* __restrict__ topi,
    const unsigned int* __restrict__ cnt, int C, int KT,
    float* __restrict__ out) {
  __shared__ float red[256];
  int tid = threadIdx.x;
  int F = (int)cnt[0];
  int M = (int)cnt[1];
  if (F == 0 || M == 0) {
    if (tid == 0) out[0] = 0.001f;
    return;
  }
  int total = KT * C * 4;
  float part = 0.0f;
  for (int e = tid; e < total; e += 256) {
    int d = e & 3;
    int q = e >> 2;
    int c = q % C;
    int i = q / C;
    int j = topi[c * KT + i];
    unsigned int orow = korig[j];
    float pred = loc[(size_t)orow * 4 + d];
    float tg = tb[c * 4 + d];
    float dd = fabsf(pred - tg);
    part += (dd < 1.0f) ? (0.5f * dd * dd) : (dd - 0.5f);
  }
  red[tid] = part;
  __syncthreads();
  for (int s = 128; s > 0; s >>= 1) {
    if (tid < s) red[tid] += red[tid + s];
    __syncthreads();
  }
  if (tid == 0) {
    float loc_loss = red[0];
    float mx = -3.402823466e+38f;
    for (int i = 0; i < KT; ++i) {
      float x = (topv[i] > 0.5f) ? 1.0f : 0.0f;   // class 0 column
      mx = fmaxf(mx, x);
    }
    float ssum = 0.0f;
    for (int i = 0; i < KT; ++i) {
      float x = (topv[i] > 0.5f) ? 1.0f : 0.0f;
      ssum += expf(x - mx);
    }
    float lse = mx + logf(ssum);
    float ce = 0.0f;
    for (int i = 0; i < KT; ++i) {
      float x = (topv[i] > 0.5f) ? 1.0f : 0.0f;
      ce += (float)labels[i] * (x - lse);
    }
    ce = -ce;
    float pt = expf(-ce);
    float om = 1.0f - pt;
    float conf_loss = 0.25f * om * om * ce;   // ALPHA=0.25, GAMMA=2
    out[0] = (loc_loss + conf_loss) / (float)M;
  }
}

// ---------------- host ------------------------------------------------------

extern "C" void kernel_launch(void* const* d_in, const int* in_sizes, int n_in,
                              void* d_out, int out_size, void* d_ws, size_t ws_size,
                              hipStream_t stream) {
  (void)n_in; (void)out_size;
  const float* loc    = (const float*)d_in[0];
  const float* conf   = (const float*)d_in[1];
  const float* tb     = (const float*)d_in[2];
  const int*   labels = (const int*)d_in[3];
  float* out = (float*)d_out;

  int N = in_sizes[0] / 4;
  if (N > NCAP) N = NCAP;
  int C  = (N > 0) ? (in_sizes[1] / N) : 20;
  int KT = in_sizes[3];

  char* ws = (char*)d_ws;
  unsigned int*       cnt   = (unsigned int*)(ws + OFF_CNT);
  unsigned long long* keys  = (unsigned long long*)(ws + OFF_KEYS);
  float*              sx1   = (float*)(ws + OFF_SX1);
  float*              sy1   = (float*)(ws + OFF_SY1);
  float*              sx2   = (float*)(ws + OFF_SX2);
  float*              sy2   = (float*)(ws + OFF_SY2);
  float*              sarea = (float*)(ws + OFF_AREA);
  unsigned int*       sorig = (unsigned int*)(ws + OFF_SORIG);
  unsigned int*       keeps = (unsigned int*)(ws + OFF_KEEPS);
  unsigned int*       korig = (unsigned int*)(ws + OFF_KORIG);
  float*              topv  = (float*)(ws + OFF_TOPV);
  int*                topi  = (int*)(ws + OFF_TOPI);
  unsigned long long* mask  = (unsigned long long*)(ws + OFF_MASK);

  bool use_mask = (ws_size >= WS_NEED_MASK);

  k_init<<<1, 64, 0, stream>>>(cnt);
  k_filter<<<NCAP / 256, 256, 0, stream>>>(conf, N, C, keys, cnt);
  k_sort<<<1, 1024, 0, stream>>>(keys);
  k_gather<<<NCAP / 256, 256, 0, stream>>>(loc, keys, sx1, sy1, sx2, sy2, sarea, sorig);
  if (use_mask) {
    k_mask<<<dim3(WROW, WROW), 64, 0, stream>>>(sx1, sy1, sx2, sy2, sarea, mask);
    k_scan<<<1, 64, 0, stream>>>(mask, cnt, keeps);
  } else {
    k_scan_nomask<<<1, 256, 0, stream>>>(sx1, sy1, sx2, sy2, sarea, cnt, keeps);
  }
  k_keptorig<<<NCAP / 256, 256, 0, stream>>>(sorig, keeps, korig, cnt);
  k_topk<<<C, 256, 0, stream>>>(conf, korig, cnt, C, KT, topv, topi);
  k_loss<<<1, 256, 0, stream>>>(loc, tb, labels, korig, topv, topi, cnt, C, KT, out);
}